// Round 5
// baseline (557.820 us; speedup 1.0000x reference)
//
#include <hip/hip_runtime.h>
#include <math.h>

#define NV 196608
#define NDEG 9
#define NC 64
#define NK 8
#define TILE 64
#define NBLK (NV / TILE)   // 3072
#define SLOT ((size_t)NV * NC)
static constexpr float EPS = 1e-5f;

typedef __attribute__((ext_vector_type(8))) short bf16x8;
typedef __attribute__((ext_vector_type(4))) short bf16x4;
typedef __attribute__((ext_vector_type(4))) float f32x4;
typedef int   i32x4u __attribute__((ext_vector_type(4), aligned(4)));
typedef float f32x4u __attribute__((ext_vector_type(4), aligned(4)));

// float -> bf16 bits, round-to-nearest-even (finite inputs)
__device__ __forceinline__ short f2bf(float f) {
    unsigned u = __float_as_uint(f);
    unsigned r = (u + 0x7fffu + ((u >> 16) & 1u)) >> 16;
    return (short)r;
}
__device__ __forceinline__ float bf2f(short h) {
    return __uint_as_float(((unsigned)(unsigned short)h) << 16);
}

// exact mish: h * tanh(softplus(h)); tanh(ln(p)) = (p^2-1)/(p^2+1), p = 1+e^h
__device__ __forceinline__ float mish_f(float h) {
    float t = __expf(fminf(h, 20.f));
    float p = 1.f + t;
    float p2 = p * p;
    return h * ((p2 - 1.f) / (p2 + 1.f));
}

// ---------------------------------------------------------------------------
// BN batch stats (blocks 0..1023) + W pre-transpose to bf16 (blocks 1024..1151).
// Wb[k][o][i] = bf16(weight[k][i][o]) -- exactly the MFMA B-fragment order.
// ---------------------------------------------------------------------------
__global__ void __launch_bounds__(256) stats_wconv_kernel(
    const float* __restrict__ x, float* __restrict__ stats,
    const float* __restrict__ w, unsigned short* __restrict__ Wb) {
    if (blockIdx.x >= 1024) {
        int idx = (blockIdx.x - 1024) * 256 + threadIdx.x;   // 32768 elements
        int i = idx & 63, o = (idx >> 6) & 63, k = idx >> 12;
        Wb[idx] = (unsigned short)f2bf(w[k * 4096 + i * 64 + o]);
        return;
    }
    const float4* x4 = (const float4*)x;
    int t = blockIdx.x * 256 + threadIdx.x;
    int stride = 1024 * 256;
    float4 s = {0.f, 0.f, 0.f, 0.f}, ss = {0.f, 0.f, 0.f, 0.f};
    for (int i = t; i < NV * (NC / 4); i += stride) {
        float4 v = x4[i];
        s.x += v.x; s.y += v.y; s.z += v.z; s.w += v.w;
        ss.x += v.x * v.x; ss.y += v.y * v.y; ss.z += v.z * v.z; ss.w += v.w * v.w;
    }
    __shared__ float4 ls[256], lss[256];
    ls[threadIdx.x] = s;
    lss[threadIdx.x] = ss;
    __syncthreads();
    if (threadIdx.x < 64) {
        int ch = threadIdx.x;
        int g = ch >> 2, comp = ch & 3;
        float a = 0.f, b = 0.f;
        #pragma unroll
        for (int k = 0; k < 16; ++k) {
            float4 v1 = ls[k * 16 + g];
            float4 v2 = lss[k * 16 + g];
            a += (comp == 0) ? v1.x : (comp == 1) ? v1.y : (comp == 2) ? v1.z : v1.w;
            b += (comp == 0) ? v2.x : (comp == 1) ? v2.y : (comp == 2) ? v2.z : v2.w;
        }
        atomicAdd(&stats[ch], a);
        atomicAdd(&stats[64 + ch], b);
    }
}

// ---------------------------------------------------------------------------
// k=0: BN apply + Mish -> basis slot 0 (bf16). Pure elementwise.
// ---------------------------------------------------------------------------
__global__ void __launch_bounds__(256) bn_mish_k0(
    const float* __restrict__ x, const float* __restrict__ stats,
    const float* __restrict__ gamma, const float* __restrict__ beta,
    unsigned short* __restrict__ dst) {
    int lane = threadIdx.x & 63;
    int wave = threadIdx.x >> 6;
    int c4 = lane & 15, rg = lane >> 4;
    int tile0 = blockIdx.x * TILE;

    float4 sc, sh;
    {
        float4 su = ((const float4*)stats)[c4];
        float4 sq = ((const float4*)stats)[16 + c4];
        float4 g4 = ((const float4*)gamma)[c4];
        float4 b4 = ((const float4*)beta)[c4];
        #define BNC(comp) { float mu = su.comp * (1.f / NV);                     \
                            float va = sq.comp * (1.f / NV) - mu * mu;           \
                            float rs = rsqrtf(va + EPS);                         \
                            sc.comp = g4.comp * rs;                              \
                            sh.comp = b4.comp - mu * sc.comp; }
        BNC(x) BNC(y) BNC(z) BNC(w)
        #undef BNC
    }

    const float4* x4 = (const float4*)x;
    #pragma unroll
    for (int it = 0; it < 4; ++it) {
        int v = tile0 + wave * 16 + it * 4 + rg;
        float4 h = x4[v * 16 + c4];
        float4 m;
        m.x = mish_f(h.x * sc.x + sh.x);
        m.y = mish_f(h.y * sc.y + sh.y);
        m.z = mish_f(h.z * sc.z + sh.z);
        m.w = mish_f(h.w * sc.w + sh.w);
        bf16x4 xb = { f2bf(m.x), f2bf(m.y), f2bf(m.z), f2bf(m.w) };
        *(bf16x4*)(dst + (size_t)v * NC + 4 * c4) = xb;
    }
}

// ---------------------------------------------------------------------------
// One Chebyshev step, bf16 in/out, fp32 arithmetic. Pure gather/stream:
//   s = L @ src; dst = FIRST ? s : 2*s - prev.
// 8 lanes per row (16 B/lane, 128 B/row coalesced). cols/vals vectorized
// (2x dwordx4 + 1) to shorten the load-dependency prefix; all streaming
// traffic nontemporal so L2 keeps the 25 MB gather working set.
// ---------------------------------------------------------------------------
template <bool FIRST>
__global__ void __launch_bounds__(256) cheb_step(
    const int* __restrict__ cols, const float* __restrict__ vals,
    const unsigned short* __restrict__ src, const unsigned short* __restrict__ prev,
    unsigned short* __restrict__ dst) {
    int lane = threadIdx.x & 63;
    int wave = threadIdx.x >> 6;
    int c8 = lane & 7, rg = lane >> 3;
    int tile0 = blockIdx.x * TILE;

    #pragma unroll
    for (int it = 0; it < 2; ++it) {
        int v = tile0 + wave * 16 + it * 8 + rg;
        const int* cp = cols + v * NDEG;
        const float* vp = vals + v * NDEG;
        i32x4u c03 = __builtin_nontemporal_load((const i32x4u*)cp);
        i32x4u c47 = __builtin_nontemporal_load((const i32x4u*)(cp + 4));
        int    cl8 = __builtin_nontemporal_load(cp + 8);
        f32x4u a03 = __builtin_nontemporal_load((const f32x4u*)vp);
        f32x4u a47 = __builtin_nontemporal_load((const f32x4u*)(vp + 4));
        float  al8 = __builtin_nontemporal_load(vp + 8);

        int   cj[NDEG] = { c03[0], c03[1], c03[2], c03[3],
                           c47[0], c47[1], c47[2], c47[3], cl8 };
        float aj[NDEG] = { a03[0], a03[1], a03[2], a03[3],
                           a47[0], a47[1], a47[2], a47[3], al8 };

        bf16x8 g[NDEG];
        #pragma unroll
        for (int j = 0; j < NDEG; ++j)
            g[j] = *(const bf16x8*)(src + (size_t)cj[j] * NC + c8 * 8);

        float s[8] = {0.f, 0.f, 0.f, 0.f, 0.f, 0.f, 0.f, 0.f};
        #pragma unroll
        for (int j = 0; j < NDEG; ++j)
            #pragma unroll
            for (int q = 0; q < 8; ++q) s[q] += aj[j] * bf2f(g[j][q]);

        bf16x8 xb;
        if (FIRST) {
            #pragma unroll
            for (int q = 0; q < 8; ++q) xb[q] = f2bf(s[q]);
        } else {
            bf16x8 p = __builtin_nontemporal_load(
                           (const bf16x8*)(prev + (size_t)v * NC + c8 * 8));
            #pragma unroll
            for (int q = 0; q < 8; ++q) xb[q] = f2bf(2.f * s[q] - bf2f(p[q]));
        }
        __builtin_nontemporal_store(xb, (bf16x8*)(dst + (size_t)v * NC + c8 * 8));
    }
}

// ---------------------------------------------------------------------------
// Deferred einsum, LDS-free: out(tile) (=|+=) sum_k basis[k%S] @ W_k (+bias).
// A-fragments are contiguous in the basis rows; B-fragments are contiguous in
// the pre-transposed Wb. Direct 16 B global loads, no LDS, no barriers.
// ---------------------------------------------------------------------------
__global__ void __launch_bounds__(256) gemm_bases(
    const unsigned short* __restrict__ basis, const unsigned short* __restrict__ Wb,
    const float* __restrict__ bias, float* __restrict__ out,
    int kb, int kc, int S, int first) {
    int lane = threadIdx.x & 63;
    int wave = threadIdx.x >> 6;
    int m16 = lane & 15, qq = lane >> 4;
    int tile0 = blockIdx.x * TILE;

    f32x4 acc[4];
    #pragma unroll
    for (int nt = 0; nt < 4; ++nt) acc[nt] = (f32x4){0.f, 0.f, 0.f, 0.f};

    #pragma unroll 1
    for (int j = 0; j < kc; ++j) {
        int k = kb + j;
        const unsigned short* bs =
            basis + (size_t)(k % S) * SLOT + (size_t)(tile0 + wave * 16 + m16) * NC;
        bf16x8 a0 = __builtin_nontemporal_load((const bf16x8*)(bs + qq * 8));
        bf16x8 a1 = __builtin_nontemporal_load((const bf16x8*)(bs + 32 + qq * 8));
        const unsigned short* wk = Wb + (size_t)k * NC * NC;
        #pragma unroll
        for (int nt = 0; nt < 4; ++nt) {
            const unsigned short* wr = wk + (nt * 16 + m16) * NC;
            bf16x8 b0 = *(const bf16x8*)(wr + qq * 8);
            bf16x8 b1 = *(const bf16x8*)(wr + 32 + qq * 8);
            acc[nt] = __builtin_amdgcn_mfma_f32_16x16x32_bf16(a0, b0, acc[nt], 0, 0, 0);
            acc[nt] = __builtin_amdgcn_mfma_f32_16x16x32_bf16(a1, b1, acc[nt], 0, 0, 0);
        }
    }

    #pragma unroll
    for (int nt = 0; nt < 4; ++nt) {
        float bcol = bias[nt * 16 + m16];
        #pragma unroll
        for (int r = 0; r < 4; ++r) {
            int vout = tile0 + wave * 16 + qq * 4 + r;
            float* po = out + (size_t)vout * NC + nt * 16 + m16;
            *po = first ? (acc[nt][r] + bcol) : (*po + acc[nt][r]);
        }
    }
}

// ---------------------------------------------------------------------------
// Inputs: (x, lap_rows, lap_cols, lap_vals, gamma, beta, weight, bias).
// lap_rows redundant (row-sorted, 9 nnz/row). cols delivered as int32.
// ws: stats[128]f32 @0 | Wb bf16[8*64*64] @1 KiB | basis ring @128 KiB.
// With S=8 (confirmed by round-4 ws_size): fixed slot per k, einsum split in
// two kc=4 passes so every basis is <=3 steps old (L3-resident) when read.
// ---------------------------------------------------------------------------
extern "C" void kernel_launch(void* const* d_in, const int* in_sizes, int n_in,
                              void* d_out, int out_size, void* d_ws, size_t ws_size,
                              hipStream_t stream) {
    const float* x      = (const float*)d_in[0];
    const int*   cols   = (const int*)  d_in[2];
    const float* vals   = (const float*)d_in[3];
    const float* gamma  = (const float*)d_in[4];
    const float* beta   = (const float*)d_in[5];
    const float* weight = (const float*)d_in[6];
    const float* bias   = (const float*)d_in[7];
    float* out = (float*)d_out;

    char* wsb = (char*)d_ws;
    float*          stats = (float*)wsb;
    unsigned short* Wb    = (unsigned short*)(wsb + 1024);
    unsigned short* basis = (unsigned short*)(wsb + 131072);

    int S = (int)((ws_size - 131072) / (SLOT * sizeof(unsigned short)));
    if (S > NK) S = NK;
    if (S < 3) S = 3;

    hipMemsetAsync(stats, 0, 1024, stream);
    stats_wconv_kernel<<<1152, 256, 0, stream>>>(x, stats, weight, Wb);
    bn_mish_k0<<<NBLK, 256, 0, stream>>>(x, stats, gamma, beta, basis);  // slot 0

    if (S >= NK) {
        // steps 1..3, einsum over bases 0..3, steps 4..7, einsum over 4..7
        for (int k = 1; k < NK; ++k) {
            const unsigned short* src = basis + (size_t)(k - 1) * SLOT;
            unsigned short*       dst = basis + (size_t)k * SLOT;
            if (k == 1) {
                cheb_step<true><<<NBLK, 256, 0, stream>>>(cols, vals, src, src, dst);
            } else {
                const unsigned short* prev = basis + (size_t)(k - 2) * SLOT;
                cheb_step<false><<<NBLK, 256, 0, stream>>>(cols, vals, src, prev, dst);
            }
            if (k == 3)
                gemm_bases<<<NBLK, 256, 0, stream>>>(basis, Wb, bias, out, 0, 4, NK, 1);
        }
        gemm_bases<<<NBLK, 256, 0, stream>>>(basis, Wb, bias, out, 4, 4, NK, 0);
    } else {
        // fallback grouping for smaller workspace (round-4 proven)
        int kb = 0, gsize = S, first = 1;
        while (kb < NK) {
            int kc = (gsize < NK - kb) ? gsize : (NK - kb);
            for (int k = (kb == 0 ? 1 : kb); k < kb + kc; ++k) {
                const unsigned short* src = basis + (size_t)((k - 1) % S) * SLOT;
                unsigned short*       dst = basis + (size_t)(k % S) * SLOT;
                if (k == 1) {
                    cheb_step<true><<<NBLK, 256, 0, stream>>>(cols, vals, src, src, dst);
                } else {
                    const unsigned short* prev = basis + (size_t)((k - 2) % S) * SLOT;
                    cheb_step<false><<<NBLK, 256, 0, stream>>>(cols, vals, src, prev, dst);
                }
            }
            gemm_bases<<<NBLK, 256, 0, stream>>>(basis, Wb, bias, out, kb, kc, S, first);
            first = 0;
            kb += kc;
            gsize = S - 2;
        }
    }
}

// Round 6
// 467.976 us; speedup vs baseline: 1.1920x; 1.1920x over previous
//
#include <hip/hip_runtime.h>
#include <math.h>

#define NV 196608
#define NDEG 9
#define NC 64
#define NK 8
#define TILE 64
#define NBLK (NV / TILE)   // 3072
#define SLOT ((size_t)NV * NC)
static constexpr float EPS = 1e-5f;

typedef __attribute__((ext_vector_type(8))) short bf16x8;
typedef __attribute__((ext_vector_type(4))) short bf16x4;
typedef __attribute__((ext_vector_type(4))) float f32x4;
typedef int   i32x4u __attribute__((ext_vector_type(4), aligned(4)));
typedef float f32x4u __attribute__((ext_vector_type(4), aligned(4)));

// float -> bf16 bits, round-to-nearest-even (finite inputs)
__device__ __forceinline__ short f2bf(float f) {
    unsigned u = __float_as_uint(f);
    unsigned r = (u + 0x7fffu + ((u >> 16) & 1u)) >> 16;
    return (short)r;
}
__device__ __forceinline__ float bf2f(short h) {
    return __uint_as_float(((unsigned)(unsigned short)h) << 16);
}

// exact mish: h * tanh(softplus(h)); tanh(ln(p)) = (p^2-1)/(p^2+1), p = 1+e^h
__device__ __forceinline__ float mish_f(float h) {
    float t = __expf(fminf(h, 20.f));
    float p = 1.f + t;
    float p2 = p * p;
    return h * ((p2 - 1.f) / (p2 + 1.f));
}

// ---------------------------------------------------------------------------
// BN batch stats (blocks 0..1023) + W pre-transpose to bf16 (blocks 1024..1151).
// Wb[k][o][i] = bf16(weight[k][i][o]) -- exactly the MFMA B-fragment order.
// ---------------------------------------------------------------------------
__global__ void __launch_bounds__(256) stats_wconv_kernel(
    const float* __restrict__ x, float* __restrict__ stats,
    const float* __restrict__ w, unsigned short* __restrict__ Wb) {
    if (blockIdx.x >= 1024) {
        int idx = (blockIdx.x - 1024) * 256 + threadIdx.x;   // 32768 elements
        int i = idx & 63, o = (idx >> 6) & 63, k = idx >> 12;
        Wb[idx] = (unsigned short)f2bf(w[k * 4096 + i * 64 + o]);
        return;
    }
    const float4* x4 = (const float4*)x;
    int t = blockIdx.x * 256 + threadIdx.x;
    int stride = 1024 * 256;
    float4 s = {0.f, 0.f, 0.f, 0.f}, ss = {0.f, 0.f, 0.f, 0.f};
    for (int i = t; i < NV * (NC / 4); i += stride) {
        float4 v = x4[i];
        s.x += v.x; s.y += v.y; s.z += v.z; s.w += v.w;
        ss.x += v.x * v.x; ss.y += v.y * v.y; ss.z += v.z * v.z; ss.w += v.w * v.w;
    }
    __shared__ float4 ls[256], lss[256];
    ls[threadIdx.x] = s;
    lss[threadIdx.x] = ss;
    __syncthreads();
    if (threadIdx.x < 64) {
        int ch = threadIdx.x;
        int g = ch >> 2, comp = ch & 3;
        float a = 0.f, b = 0.f;
        #pragma unroll
        for (int k = 0; k < 16; ++k) {
            float4 v1 = ls[k * 16 + g];
            float4 v2 = lss[k * 16 + g];
            a += (comp == 0) ? v1.x : (comp == 1) ? v1.y : (comp == 2) ? v1.z : v1.w;
            b += (comp == 0) ? v2.x : (comp == 1) ? v2.y : (comp == 2) ? v2.z : v2.w;
        }
        atomicAdd(&stats[ch], a);
        atomicAdd(&stats[64 + ch], b);
    }
}

// ---------------------------------------------------------------------------
// k=0: BN apply + Mish -> basis slot 0 (bf16). Pure elementwise.
// ---------------------------------------------------------------------------
__global__ void __launch_bounds__(256) bn_mish_k0(
    const float* __restrict__ x, const float* __restrict__ stats,
    const float* __restrict__ gamma, const float* __restrict__ beta,
    unsigned short* __restrict__ dst) {
    int lane = threadIdx.x & 63;
    int wave = threadIdx.x >> 6;
    int c4 = lane & 15, rg = lane >> 4;
    int tile0 = blockIdx.x * TILE;

    float4 sc, sh;
    {
        float4 su = ((const float4*)stats)[c4];
        float4 sq = ((const float4*)stats)[16 + c4];
        float4 g4 = ((const float4*)gamma)[c4];
        float4 b4 = ((const float4*)beta)[c4];
        #define BNC(comp) { float mu = su.comp * (1.f / NV);                     \
                            float va = sq.comp * (1.f / NV) - mu * mu;           \
                            float rs = rsqrtf(va + EPS);                         \
                            sc.comp = g4.comp * rs;                              \
                            sh.comp = b4.comp - mu * sc.comp; }
        BNC(x) BNC(y) BNC(z) BNC(w)
        #undef BNC
    }

    const float4* x4 = (const float4*)x;
    #pragma unroll
    for (int it = 0; it < 4; ++it) {
        int v = tile0 + wave * 16 + it * 4 + rg;
        float4 h = x4[v * 16 + c4];
        float4 m;
        m.x = mish_f(h.x * sc.x + sh.x);
        m.y = mish_f(h.y * sc.y + sh.y);
        m.z = mish_f(h.z * sc.z + sh.z);
        m.w = mish_f(h.w * sc.w + sh.w);
        bf16x4 xb = { f2bf(m.x), f2bf(m.y), f2bf(m.z), f2bf(m.w) };
        *(bf16x4*)(dst + (size_t)v * NC + 4 * c4) = xb;
    }
}

// ---------------------------------------------------------------------------
// One Chebyshev step, bf16 in/out, fp32 arithmetic (round-5 version, kept).
// ---------------------------------------------------------------------------
template <bool FIRST>
__global__ void __launch_bounds__(256) cheb_step(
    const int* __restrict__ cols, const float* __restrict__ vals,
    const unsigned short* __restrict__ src, const unsigned short* __restrict__ prev,
    unsigned short* __restrict__ dst) {
    int lane = threadIdx.x & 63;
    int wave = threadIdx.x >> 6;
    int c8 = lane & 7, rg = lane >> 3;
    int tile0 = blockIdx.x * TILE;

    #pragma unroll
    for (int it = 0; it < 2; ++it) {
        int v = tile0 + wave * 16 + it * 8 + rg;
        const int* cp = cols + v * NDEG;
        const float* vp = vals + v * NDEG;
        i32x4u c03 = __builtin_nontemporal_load((const i32x4u*)cp);
        i32x4u c47 = __builtin_nontemporal_load((const i32x4u*)(cp + 4));
        int    cl8 = __builtin_nontemporal_load(cp + 8);
        f32x4u a03 = __builtin_nontemporal_load((const f32x4u*)vp);
        f32x4u a47 = __builtin_nontemporal_load((const f32x4u*)(vp + 4));
        float  al8 = __builtin_nontemporal_load(vp + 8);

        int   cj[NDEG] = { c03[0], c03[1], c03[2], c03[3],
                           c47[0], c47[1], c47[2], c47[3], cl8 };
        float aj[NDEG] = { a03[0], a03[1], a03[2], a03[3],
                           a47[0], a47[1], a47[2], a47[3], al8 };

        bf16x8 g[NDEG];
        #pragma unroll
        for (int j = 0; j < NDEG; ++j)
            g[j] = *(const bf16x8*)(src + (size_t)cj[j] * NC + c8 * 8);

        float s[8] = {0.f, 0.f, 0.f, 0.f, 0.f, 0.f, 0.f, 0.f};
        #pragma unroll
        for (int j = 0; j < NDEG; ++j)
            #pragma unroll
            for (int q = 0; q < 8; ++q) s[q] += aj[j] * bf2f(g[j][q]);

        bf16x8 xb;
        if (FIRST) {
            #pragma unroll
            for (int q = 0; q < 8; ++q) xb[q] = f2bf(s[q]);
        } else {
            bf16x8 p = __builtin_nontemporal_load(
                           (const bf16x8*)(prev + (size_t)v * NC + c8 * 8));
            #pragma unroll
            for (int q = 0; q < 8; ++q) xb[q] = f2bf(2.f * s[q] - bf2f(p[q]));
        }
        __builtin_nontemporal_store(xb, (bf16x8*)(dst + (size_t)v * NC + c8 * 8));
    }
}

// ---------------------------------------------------------------------------
// Single deferred einsum over ALL 8 bases: out = sum_k basis[k] @ W_k + bias.
// - All 8 W_k staged in LDS once (XOR-chunk swizzle, <=2-way banks, 1 barrier).
// - A-tiles are WAVE-PRIVATE: each wave stages its own 16 rows into a private
//   double-buffered LDS region -> no __syncthreads in the K-loop.
// - 2-deep register prefetch of A hides L3 latency behind 2 iters of compute.
// LDS: 64 KB W + 16 KB A = 80 KB -> exactly 2 blocks/CU.
// ---------------------------------------------------------------------------
__global__ void __launch_bounds__(256) gemm_all(
    const unsigned short* __restrict__ basis, const unsigned short* __restrict__ Wb,
    const float* __restrict__ bias, float* __restrict__ out) {
    __shared__ short Wl[NK * NC * NC];      // 64 KB
    __shared__ short At[2][4][1024];        // 16 KB: [buf][wave][16 rows x 64]

    const int tid  = threadIdx.x;
    const int lane = tid & 63;
    const int wave = tid >> 6;
    const int m16  = lane & 15, qq = lane >> 4;
    const int tile0 = blockIdx.x * TILE;

    // ---- stage all 8 W_k, swizzled: chunk (o,c) -> o*64 + ((c^(o&7))*8) ----
    #pragma unroll
    for (int h = 0; h < 16; ++h) {
        int ci = tid + h * 256;             // 4096 chunks of 8 shorts
        int k = ci >> 9, o = (ci >> 3) & 63, c = ci & 7;
        bf16x8 w = *(const bf16x8*)(Wb + (size_t)ci * 8);
        *(bf16x8*)&Wl[k * 4096 + o * 64 + ((c ^ (o & 7)) * 8)] = w;
    }
    __syncthreads();                        // the ONLY block-wide barrier

    // wave-private A staging: lane stages chunks (r0,c) and (r0+8,c)
    const int r0 = lane >> 3;               // 0..7
    const int cc = lane & 7;                // chunk col 0..7
    const unsigned short* abase = basis + (size_t)(tile0 + wave * 16) * NC;
    short* mybuf0 = &At[0][wave][0];
    short* mybuf1 = &At[1][wave][0];

    #define ALOAD(dst0, dst1, k_)                                                  \
        { const unsigned short* p = abase + (size_t)(k_) * SLOT;                   \
          dst0 = __builtin_nontemporal_load((const bf16x8*)(p + r0 * 64 + cc * 8));\
          dst1 = __builtin_nontemporal_load((const bf16x8*)(p + (r0 + 8) * 64 + cc * 8)); }
    #define AWRITE(buf, s0, s1)                                                    \
        { *(bf16x8*)&buf[r0 * 64 + ((cc ^ (r0 & 7)) * 8)] = s0;                    \
          *(bf16x8*)&buf[(r0 + 8) * 64 + ((cc ^ ((r0 + 8) & 7)) * 8)] = s1; }

    bf16x8 p00, p01, p10, p11;
    ALOAD(p00, p01, 0)
    ALOAD(p10, p11, 1)
    AWRITE(mybuf0, p00, p01)                // buf0 <- A0

    f32x4 acc[4];
    #pragma unroll
    for (int nt = 0; nt < 4; ++nt) acc[nt] = (f32x4){0.f, 0.f, 0.f, 0.f};

    #pragma unroll
    for (int k = 0; k < NK; ++k) {
        // prefetch A_{k+2} into the register pair just freed
        if (k + 2 < NK) {
            if ((k & 1) == 0) { ALOAD(p00, p01, k + 2) }
            else              { ALOAD(p10, p11, k + 2) }
        }
        // compute from buf[k&1] (wave-private, lgkm-ordered)
        const short* ab = (k & 1) ? mybuf1 : mybuf0;
        bf16x8 a0 = *(const bf16x8*)&ab[m16 * 64 + ((qq ^ (m16 & 7)) * 8)];
        bf16x8 a1 = *(const bf16x8*)&ab[m16 * 64 + (((qq + 4) ^ (m16 & 7)) * 8)];
        const short* wk = &Wl[k * 4096];
        #pragma unroll
        for (int nt = 0; nt < 4; ++nt) {
            int o = nt * 16 + m16;
            bf16x8 b0 = *(const bf16x8*)&wk[o * 64 + ((qq ^ (o & 7)) * 8)];
            bf16x8 b1 = *(const bf16x8*)&wk[o * 64 + (((qq + 4) ^ (o & 7)) * 8)];
            acc[nt] = __builtin_amdgcn_mfma_f32_16x16x32_bf16(a0, b0, acc[nt], 0, 0, 0);
            acc[nt] = __builtin_amdgcn_mfma_f32_16x16x32_bf16(a1, b1, acc[nt], 0, 0, 0);
        }
        // write A_{k+1} into the other buffer
        if (k + 1 < NK) {
            short* nb = (k & 1) ? mybuf0 : mybuf1;
            if ((k & 1) == 0) { AWRITE(nb, p10, p11) }
            else              { AWRITE(nb, p00, p01) }
        }
    }
    #undef ALOAD
    #undef AWRITE

    #pragma unroll
    for (int nt = 0; nt < 4; ++nt) {
        float bcol = bias[nt * 16 + m16];
        #pragma unroll
        for (int r = 0; r < 4; ++r) {
            int vout = tile0 + wave * 16 + qq * 4 + r;
            out[(size_t)vout * NC + nt * 16 + m16] = acc[nt][r] + bcol;
        }
    }
}

// ---------------------------------------------------------------------------
// Fallback einsum (small-ws path only): LDS-free grouped gemm.
// ---------------------------------------------------------------------------
__global__ void __launch_bounds__(256) gemm_bases(
    const unsigned short* __restrict__ basis, const unsigned short* __restrict__ Wb,
    const float* __restrict__ bias, float* __restrict__ out,
    int kb, int kc, int S, int first) {
    int lane = threadIdx.x & 63;
    int wave = threadIdx.x >> 6;
    int m16 = lane & 15, qq = lane >> 4;
    int tile0 = blockIdx.x * TILE;

    f32x4 acc[4];
    #pragma unroll
    for (int nt = 0; nt < 4; ++nt) acc[nt] = (f32x4){0.f, 0.f, 0.f, 0.f};

    #pragma unroll 1
    for (int j = 0; j < kc; ++j) {
        int k = kb + j;
        const unsigned short* bs =
            basis + (size_t)(k % S) * SLOT + (size_t)(tile0 + wave * 16 + m16) * NC;
        bf16x8 a0 = __builtin_nontemporal_load((const bf16x8*)(bs + qq * 8));
        bf16x8 a1 = __builtin_nontemporal_load((const bf16x8*)(bs + 32 + qq * 8));
        const unsigned short* wk = Wb + (size_t)k * NC * NC;
        #pragma unroll
        for (int nt = 0; nt < 4; ++nt) {
            const unsigned short* wr = wk + (nt * 16 + m16) * NC;
            bf16x8 b0 = *(const bf16x8*)(wr + qq * 8);
            bf16x8 b1 = *(const bf16x8*)(wr + 32 + qq * 8);
            acc[nt] = __builtin_amdgcn_mfma_f32_16x16x32_bf16(a0, b0, acc[nt], 0, 0, 0);
            acc[nt] = __builtin_amdgcn_mfma_f32_16x16x32_bf16(a1, b1, acc[nt], 0, 0, 0);
        }
    }

    #pragma unroll
    for (int nt = 0; nt < 4; ++nt) {
        float bcol = bias[nt * 16 + m16];
        #pragma unroll
        for (int r = 0; r < 4; ++r) {
            int vout = tile0 + wave * 16 + qq * 4 + r;
            float* po = out + (size_t)vout * NC + nt * 16 + m16;
            *po = first ? (acc[nt][r] + bcol) : (*po + acc[nt][r]);
        }
    }
}

// ---------------------------------------------------------------------------
// Inputs: (x, lap_rows, lap_cols, lap_vals, gamma, beta, weight, bias).
// lap_rows redundant (row-sorted, 9 nnz/row). cols delivered as int32.
// ws: stats[128]f32 @0 | Wb bf16[8*64*64] @1 KiB | basis ring @128 KiB.
// S=8 confirmed by rounds 4/5 -> single gemm_all over all 8 bases.
// ---------------------------------------------------------------------------
extern "C" void kernel_launch(void* const* d_in, const int* in_sizes, int n_in,
                              void* d_out, int out_size, void* d_ws, size_t ws_size,
                              hipStream_t stream) {
    const float* x      = (const float*)d_in[0];
    const int*   cols   = (const int*)  d_in[2];
    const float* vals   = (const float*)d_in[3];
    const float* gamma  = (const float*)d_in[4];
    const float* beta   = (const float*)d_in[5];
    const float* weight = (const float*)d_in[6];
    const float* bias   = (const float*)d_in[7];
    float* out = (float*)d_out;

    char* wsb = (char*)d_ws;
    float*          stats = (float*)wsb;
    unsigned short* Wb    = (unsigned short*)(wsb + 1024);
    unsigned short* basis = (unsigned short*)(wsb + 131072);

    int S = (int)((ws_size - 131072) / (SLOT * sizeof(unsigned short)));
    if (S > NK) S = NK;
    if (S < 3) S = 3;

    hipMemsetAsync(stats, 0, 1024, stream);
    stats_wconv_kernel<<<1152, 256, 0, stream>>>(x, stats, weight, Wb);
    bn_mish_k0<<<NBLK, 256, 0, stream>>>(x, stats, gamma, beta, basis);  // slot 0

    if (S >= NK) {
        for (int k = 1; k < NK; ++k) {
            const unsigned short* src = basis + (size_t)(k - 1) * SLOT;
            unsigned short*       dst = basis + (size_t)k * SLOT;
            if (k == 1) {
                cheb_step<true><<<NBLK, 256, 0, stream>>>(cols, vals, src, src, dst);
            } else {
                const unsigned short* prev = basis + (size_t)(k - 2) * SLOT;
                cheb_step<false><<<NBLK, 256, 0, stream>>>(cols, vals, src, prev, dst);
            }
        }
        gemm_all<<<NBLK, 256, 0, stream>>>(basis, Wb, bias, out);
    } else {
        int kb = 0, gsize = S, first = 1;
        while (kb < NK) {
            int kc = (gsize < NK - kb) ? gsize : (NK - kb);
            for (int k = (kb == 0 ? 1 : kb); k < kb + kc; ++k) {
                const unsigned short* src = basis + (size_t)((k - 1) % S) * SLOT;
                unsigned short*       dst = basis + (size_t)(k % S) * SLOT;
                if (k == 1) {
                    cheb_step<true><<<NBLK, 256, 0, stream>>>(cols, vals, src, src, dst);
                } else {
                    const unsigned short* prev = basis + (size_t)((k - 2) % S) * SLOT;
                    cheb_step<false><<<NBLK, 256, 0, stream>>>(cols, vals, src, prev, dst);
                }
            }
            gemm_bases<<<NBLK, 256, 0, stream>>>(basis, Wb, bias, out, kb, kc, S, first);
            first = 0;
            kb += kc;
            gsize = S - 2;
        }
    }
}

// Round 7
// 446.828 us; speedup vs baseline: 1.2484x; 1.0473x over previous
//
#include <hip/hip_runtime.h>
#include <math.h>

#define NV 196608
#define NDEG 9
#define NC 64
#define NK 8
#define TILE 64
#define NBLK (NV / TILE)   // 3072
#define SLOT ((size_t)NV * NC)
static constexpr float EPS = 1e-5f;

typedef __attribute__((ext_vector_type(8))) short bf16x8;
typedef __attribute__((ext_vector_type(4))) short bf16x4;
typedef __attribute__((ext_vector_type(4))) float f32x4;
typedef int   i32x4u __attribute__((ext_vector_type(4), aligned(4)));
typedef float f32x4u __attribute__((ext_vector_type(4), aligned(4)));

// float -> bf16 bits, round-to-nearest-even (finite inputs)
__device__ __forceinline__ short f2bf(float f) {
    unsigned u = __float_as_uint(f);
    unsigned r = (u + 0x7fffu + ((u >> 16) & 1u)) >> 16;
    return (short)r;
}
__device__ __forceinline__ float bf2f(short h) {
    return __uint_as_float(((unsigned)(unsigned short)h) << 16);
}

// exact mish: h * tanh(softplus(h)); tanh(ln(p)) = (p^2-1)/(p^2+1), p = 1+e^h
__device__ __forceinline__ float mish_f(float h) {
    float t = __expf(fminf(h, 20.f));
    float p = 1.f + t;
    float p2 = p * p;
    return h * ((p2 - 1.f) / (p2 + 1.f));
}

// LDS tile address: row-stride 64 shorts, 8-short chunks XOR-swizzled.
// Staging writes: 8 lanes x 16 B = exactly 32 banks per 8 lanes -> <=2-way (free).
// Fragment reads: measured 0 conflicts in round 6 with this layout.
#define LDSOFF(r, c) ((r) * 64 + (((c) ^ ((r) & 7)) * 8))

// ---------------------------------------------------------------------------
// BN batch stats (blocks 0..1023) + W pre-transpose to bf16 (blocks 1024..1151).
// Wb[k][o][i] = bf16(weight[k][i][o]) -- exactly the MFMA B-fragment order.
// ---------------------------------------------------------------------------
__global__ void __launch_bounds__(256) stats_wconv_kernel(
    const float* __restrict__ x, float* __restrict__ stats,
    const float* __restrict__ w, unsigned short* __restrict__ Wb) {
    if (blockIdx.x >= 1024) {
        int idx = (blockIdx.x - 1024) * 256 + threadIdx.x;   // 32768 elements
        int i = idx & 63, o = (idx >> 6) & 63, k = idx >> 12;
        Wb[idx] = (unsigned short)f2bf(w[k * 4096 + i * 64 + o]);
        return;
    }
    const float4* x4 = (const float4*)x;
    int t = blockIdx.x * 256 + threadIdx.x;
    int stride = 1024 * 256;
    float4 s = {0.f, 0.f, 0.f, 0.f}, ss = {0.f, 0.f, 0.f, 0.f};
    for (int i = t; i < NV * (NC / 4); i += stride) {
        float4 v = x4[i];
        s.x += v.x; s.y += v.y; s.z += v.z; s.w += v.w;
        ss.x += v.x * v.x; ss.y += v.y * v.y; ss.z += v.z * v.z; ss.w += v.w * v.w;
    }
    __shared__ float4 ls[256], lss[256];
    ls[threadIdx.x] = s;
    lss[threadIdx.x] = ss;
    __syncthreads();
    if (threadIdx.x < 64) {
        int ch = threadIdx.x;
        int g = ch >> 2, comp = ch & 3;
        float a = 0.f, b = 0.f;
        #pragma unroll
        for (int k = 0; k < 16; ++k) {
            float4 v1 = ls[k * 16 + g];
            float4 v2 = lss[k * 16 + g];
            a += (comp == 0) ? v1.x : (comp == 1) ? v1.y : (comp == 2) ? v1.z : v1.w;
            b += (comp == 0) ? v2.x : (comp == 1) ? v2.y : (comp == 2) ? v2.z : v2.w;
        }
        atomicAdd(&stats[ch], a);
        atomicAdd(&stats[64 + ch], b);
    }
}

// ---------------------------------------------------------------------------
// k=0: BN apply + Mish -> basis slot 0 (bf16). Pure elementwise.
// ---------------------------------------------------------------------------
__global__ void __launch_bounds__(256) bn_mish_k0(
    const float* __restrict__ x, const float* __restrict__ stats,
    const float* __restrict__ gamma, const float* __restrict__ beta,
    unsigned short* __restrict__ dst) {
    int lane = threadIdx.x & 63;
    int wave = threadIdx.x >> 6;
    int c4 = lane & 15, rg = lane >> 4;
    int tile0 = blockIdx.x * TILE;

    float4 sc, sh;
    {
        float4 su = ((const float4*)stats)[c4];
        float4 sq = ((const float4*)stats)[16 + c4];
        float4 g4 = ((const float4*)gamma)[c4];
        float4 b4 = ((const float4*)beta)[c4];
        #define BNC(comp) { float mu = su.comp * (1.f / NV);                     \
                            float va = sq.comp * (1.f / NV) - mu * mu;           \
                            float rs = rsqrtf(va + EPS);                         \
                            sc.comp = g4.comp * rs;                              \
                            sh.comp = b4.comp - mu * sc.comp; }
        BNC(x) BNC(y) BNC(z) BNC(w)
        #undef BNC
    }

    const float4* x4 = (const float4*)x;
    #pragma unroll
    for (int it = 0; it < 4; ++it) {
        int v = tile0 + wave * 16 + it * 4 + rg;
        float4 h = x4[v * 16 + c4];
        float4 m;
        m.x = mish_f(h.x * sc.x + sh.x);
        m.y = mish_f(h.y * sc.y + sh.y);
        m.z = mish_f(h.z * sc.z + sh.z);
        m.w = mish_f(h.w * sc.w + sh.w);
        bf16x4 xb = { f2bf(m.x), f2bf(m.y), f2bf(m.z), f2bf(m.w) };
        *(bf16x4*)(dst + (size_t)v * NC + 4 * c4) = xb;
    }
}

// ---------------------------------------------------------------------------
// One Chebyshev step, bf16 in/out, fp32 arithmetic.
//   s = L @ src; dst = FIRST ? s : 2*s - prev.
// Cache policy: cols/vals/dst are re-read by later steps -> PLAIN (retained);
// prev is dead after the read -> nontemporal load only.
// ---------------------------------------------------------------------------
template <bool FIRST>
__global__ void __launch_bounds__(256) cheb_step(
    const int* __restrict__ cols, const float* __restrict__ vals,
    const unsigned short* __restrict__ src, const unsigned short* __restrict__ prev,
    unsigned short* __restrict__ dst) {
    int lane = threadIdx.x & 63;
    int wave = threadIdx.x >> 6;
    int c8 = lane & 7, rg = lane >> 3;
    int tile0 = blockIdx.x * TILE;

    #pragma unroll
    for (int it = 0; it < 2; ++it) {
        int v = tile0 + wave * 16 + it * 8 + rg;
        const int* cp = cols + v * NDEG;
        const float* vp = vals + v * NDEG;
        i32x4u c03 = *(const i32x4u*)cp;
        i32x4u c47 = *(const i32x4u*)(cp + 4);
        int    cl8 = cp[8];
        f32x4u a03 = *(const f32x4u*)vp;
        f32x4u a47 = *(const f32x4u*)(vp + 4);
        float  al8 = vp[8];

        int   cj[NDEG] = { c03[0], c03[1], c03[2], c03[3],
                           c47[0], c47[1], c47[2], c47[3], cl8 };
        float aj[NDEG] = { a03[0], a03[1], a03[2], a03[3],
                           a47[0], a47[1], a47[2], a47[3], al8 };

        bf16x8 g[NDEG];
        #pragma unroll
        for (int j = 0; j < NDEG; ++j)
            g[j] = *(const bf16x8*)(src + (size_t)cj[j] * NC + c8 * 8);

        float s[8] = {0.f, 0.f, 0.f, 0.f, 0.f, 0.f, 0.f, 0.f};
        #pragma unroll
        for (int j = 0; j < NDEG; ++j)
            #pragma unroll
            for (int q = 0; q < 8; ++q) s[q] += aj[j] * bf2f(g[j][q]);

        bf16x8 xb;
        if (FIRST) {
            #pragma unroll
            for (int q = 0; q < 8; ++q) xb[q] = f2bf(s[q]);
        } else {
            bf16x8 p = __builtin_nontemporal_load(
                           (const bf16x8*)(prev + (size_t)v * NC + c8 * 8));
            #pragma unroll
            for (int q = 0; q < 8; ++q) xb[q] = f2bf(2.f * s[q] - bf2f(p[q]));
        }
        *(bf16x8*)(dst + (size_t)v * NC + c8 * 8) = xb;
    }
}

// ---------------------------------------------------------------------------
// Single einsum over ALL 8 bases: out = sum_k basis[k] @ W_k + bias.
// Per-k double-buffered LDS staging of A-tile AND W_k (32 KB total -> 5
// blocks/CU, ~20 waves/CU for HBM latency hiding), stride-64 XOR-swizzle
// (0 conflicts, proven round 6), k+1 global prefetch issued before compute k.
// ---------------------------------------------------------------------------
__global__ void __launch_bounds__(256) gemm_all(
    const unsigned short* __restrict__ basis, const unsigned short* __restrict__ Wb,
    const float* __restrict__ bias, float* __restrict__ out) {
    __shared__ short Al[2][NC * NC];   // 2 x 8 KB
    __shared__ short Wl[2][NC * NC];   // 2 x 8 KB

    const int tid  = threadIdx.x;
    const int lane = tid & 63;
    const int wave = tid >> 6;
    const int m16  = lane & 15, qq = lane >> 4;
    const int tile0 = blockIdx.x * TILE;

    // staging chunks: thread t handles chunk t (row rA) and chunk t+256 (rA+32)
    const int rA = tid >> 3, cA = tid & 7;

    bf16x8 pa0, pa1, pw0, pw1;
    {   // prologue: k = 0 -> buf 0
        const unsigned short* bp = basis + (size_t)(tile0 + rA) * NC + cA * 8;
        pa0 = __builtin_nontemporal_load((const bf16x8*)bp);
        pa1 = __builtin_nontemporal_load((const bf16x8*)(bp + 32 * NC));
        pw0 = *(const bf16x8*)(Wb + rA * NC + cA * 8);
        pw1 = *(const bf16x8*)(Wb + (rA + 32) * NC + cA * 8);
        *(bf16x8*)&Al[0][LDSOFF(rA, cA)] = pa0;
        *(bf16x8*)&Al[0][LDSOFF(rA + 32, cA)] = pa1;
        *(bf16x8*)&Wl[0][LDSOFF(rA, cA)] = pw0;
        *(bf16x8*)&Wl[0][LDSOFF(rA + 32, cA)] = pw1;
    }
    __syncthreads();

    f32x4 acc[4];
    #pragma unroll
    for (int nt = 0; nt < 4; ++nt) acc[nt] = (f32x4){0.f, 0.f, 0.f, 0.f};

    #pragma unroll
    for (int k = 0; k < NK; ++k) {
        // issue global prefetch for k+1 (lands during compute of k)
        if (k + 1 < NK) {
            const unsigned short* bp =
                basis + (size_t)(k + 1) * SLOT + (size_t)(tile0 + rA) * NC + cA * 8;
            pa0 = __builtin_nontemporal_load((const bf16x8*)bp);
            pa1 = __builtin_nontemporal_load((const bf16x8*)(bp + 32 * NC));
            const unsigned short* wp = Wb + (k + 1) * NC * NC;
            pw0 = *(const bf16x8*)(wp + rA * NC + cA * 8);
            pw1 = *(const bf16x8*)(wp + (rA + 32) * NC + cA * 8);
        }
        // compute k from buf[k&1]
        const short* ab = Al[k & 1];
        const short* wb = Wl[k & 1];
        bf16x8 a0 = *(const bf16x8*)&ab[LDSOFF(wave * 16 + m16, qq)];
        bf16x8 a1 = *(const bf16x8*)&ab[LDSOFF(wave * 16 + m16, qq + 4)];
        #pragma unroll
        for (int nt = 0; nt < 4; ++nt) {
            int o = nt * 16 + m16;
            bf16x8 b0 = *(const bf16x8*)&wb[LDSOFF(o, qq)];
            bf16x8 b1 = *(const bf16x8*)&wb[LDSOFF(o, qq + 4)];
            acc[nt] = __builtin_amdgcn_mfma_f32_16x16x32_bf16(a0, b0, acc[nt], 0, 0, 0);
            acc[nt] = __builtin_amdgcn_mfma_f32_16x16x32_bf16(a1, b1, acc[nt], 0, 0, 0);
        }
        // store prefetched k+1 into the other buffer, then barrier
        if (k + 1 < NK) {
            short* an = Al[(k + 1) & 1];
            short* wn = Wl[(k + 1) & 1];
            *(bf16x8*)&an[LDSOFF(rA, cA)] = pa0;
            *(bf16x8*)&an[LDSOFF(rA + 32, cA)] = pa1;
            *(bf16x8*)&wn[LDSOFF(rA, cA)] = pw0;
            *(bf16x8*)&wn[LDSOFF(rA + 32, cA)] = pw1;
            __syncthreads();
        }
    }

    #pragma unroll
    for (int nt = 0; nt < 4; ++nt) {
        float bcol = bias[nt * 16 + m16];
        #pragma unroll
        for (int r = 0; r < 4; ++r) {
            int vout = tile0 + wave * 16 + qq * 4 + r;
            out[(size_t)vout * NC + nt * 16 + m16] = acc[nt][r] + bcol;
        }
    }
}

// ---------------------------------------------------------------------------
// Fallback einsum (small-ws path only): LDS-free grouped gemm.
// ---------------------------------------------------------------------------
__global__ void __launch_bounds__(256) gemm_bases(
    const unsigned short* __restrict__ basis, const unsigned short* __restrict__ Wb,
    const float* __restrict__ bias, float* __restrict__ out,
    int kb, int kc, int S, int first) {
    int lane = threadIdx.x & 63;
    int wave = threadIdx.x >> 6;
    int m16 = lane & 15, qq = lane >> 4;
    int tile0 = blockIdx.x * TILE;

    f32x4 acc[4];
    #pragma unroll
    for (int nt = 0; nt < 4; ++nt) acc[nt] = (f32x4){0.f, 0.f, 0.f, 0.f};

    #pragma unroll 1
    for (int j = 0; j < kc; ++j) {
        int k = kb + j;
        const unsigned short* bs =
            basis + (size_t)(k % S) * SLOT + (size_t)(tile0 + wave * 16 + m16) * NC;
        bf16x8 a0 = *(const bf16x8*)(bs + qq * 8);
        bf16x8 a1 = *(const bf16x8*)(bs + 32 + qq * 8);
        const unsigned short* wk = Wb + (size_t)k * NC * NC;
        #pragma unroll
        for (int nt = 0; nt < 4; ++nt) {
            const unsigned short* wr = wk + (nt * 16 + m16) * NC;
            bf16x8 b0 = *(const bf16x8*)(wr + qq * 8);
            bf16x8 b1 = *(const bf16x8*)(wr + 32 + qq * 8);
            acc[nt] = __builtin_amdgcn_mfma_f32_16x16x32_bf16(a0, b0, acc[nt], 0, 0, 0);
            acc[nt] = __builtin_amdgcn_mfma_f32_16x16x32_bf16(a1, b1, acc[nt], 0, 0, 0);
        }
    }

    #pragma unroll
    for (int nt = 0; nt < 4; ++nt) {
        float bcol = bias[nt * 16 + m16];
        #pragma unroll
        for (int r = 0; r < 4; ++r) {
            int vout = tile0 + wave * 16 + qq * 4 + r;
            float* po = out + (size_t)vout * NC + nt * 16 + m16;
            *po = first ? (acc[nt][r] + bcol) : (*po + acc[nt][r]);
        }
    }
}

// ---------------------------------------------------------------------------
// Inputs: (x, lap_rows, lap_cols, lap_vals, gamma, beta, weight, bias).
// lap_rows redundant (row-sorted, 9 nnz/row). cols delivered as int32.
// ws: stats[128]f32 @0 | Wb bf16[8*64*64] @1 KiB | basis ring @128 KiB.
// ---------------------------------------------------------------------------
extern "C" void kernel_launch(void* const* d_in, const int* in_sizes, int n_in,
                              void* d_out, int out_size, void* d_ws, size_t ws_size,
                              hipStream_t stream) {
    const float* x      = (const float*)d_in[0];
    const int*   cols   = (const int*)  d_in[2];
    const float* vals   = (const float*)d_in[3];
    const float* gamma  = (const float*)d_in[4];
    const float* beta   = (const float*)d_in[5];
    const float* weight = (const float*)d_in[6];
    const float* bias   = (const float*)d_in[7];
    float* out = (float*)d_out;

    char* wsb = (char*)d_ws;
    float*          stats = (float*)wsb;
    unsigned short* Wb    = (unsigned short*)(wsb + 1024);
    unsigned short* basis = (unsigned short*)(wsb + 131072);

    int S = (int)((ws_size - 131072) / (SLOT * sizeof(unsigned short)));
    if (S > NK) S = NK;
    if (S < 3) S = 3;

    hipMemsetAsync(stats, 0, 1024, stream);
    stats_wconv_kernel<<<1152, 256, 0, stream>>>(x, stats, weight, Wb);
    bn_mish_k0<<<NBLK, 256, 0, stream>>>(x, stats, gamma, beta, basis);  // slot 0

    if (S >= NK) {
        for (int k = 1; k < NK; ++k) {
            const unsigned short* src = basis + (size_t)(k - 1) * SLOT;
            unsigned short*       dst = basis + (size_t)k * SLOT;
            if (k == 1) {
                cheb_step<true><<<NBLK, 256, 0, stream>>>(cols, vals, src, src, dst);
            } else {
                const unsigned short* prev = basis + (size_t)(k - 2) * SLOT;
                cheb_step<false><<<NBLK, 256, 0, stream>>>(cols, vals, src, prev, dst);
            }
        }
        gemm_all<<<NBLK, 256, 0, stream>>>(basis, Wb, bias, out);
    } else {
        int kb = 0, gsize = S, first = 1;
        while (kb < NK) {
            int kc = (gsize < NK - kb) ? gsize : (NK - kb);
            for (int k = (kb == 0 ? 1 : kb); k < kb + kc; ++k) {
                const unsigned short* src = basis + (size_t)((k - 1) % S) * SLOT;
                unsigned short*       dst = basis + (size_t)(k % S) * SLOT;
                if (k == 1) {
                    cheb_step<true><<<NBLK, 256, 0, stream>>>(cols, vals, src, src, dst);
                } else {
                    const unsigned short* prev = basis + (size_t)((k - 2) % S) * SLOT;
                    cheb_step<false><<<NBLK, 256, 0, stream>>>(cols, vals, src, prev, dst);
                }
            }
            gemm_bases<<<NBLK, 256, 0, stream>>>(basis, Wb, bias, out, kb, kc, S, first);
            first = 0;
            kb += kc;
            gsize = S - 2;
        }
    }
}